// Round 1
// baseline (1033.671 us; speedup 1.0000x reference)
//
#include <hip/hip_runtime.h>
#include <hip/hip_bf16.h>

#define DI 768
#define SS 2048
#define NBATCH 8
#define QK_ELEMS ((size_t)16384 * 768)

typedef float f32x4 __attribute__((ext_vector_type(4)));
typedef short s16x8 __attribute__((ext_vector_type(8)));
typedef short s16x4 __attribute__((ext_vector_type(4)));

static __device__ __forceinline__ unsigned short f2bf(float f) {
    union { float f; unsigned int u; } a; a.f = f;
    unsigned int r = (a.u + 0x7FFFu + ((a.u >> 16) & 1u)) >> 16; // RNE
    return (unsigned short)r;
}

// ---------------- projection: Q = x@wq (pre-scaled), K = x@wk, Vt = (x@wv)^T ----
// grid (6, 128, 3), block 256. 128x128 tile, BK=32, 4 waves each 64x64.
__global__ __launch_bounds__(256) void proj_kernel(
    const float* __restrict__ x, const float* __restrict__ wq,
    const float* __restrict__ wk, const float* __restrict__ wv,
    unsigned short* __restrict__ ws)
{
    constexpr int LDT = 40; // padded LDS stride (80B: 16B-aligned rows, conflict-light)
    __shared__ unsigned short As[128 * LDT];
    __shared__ unsigned short Bs[128 * LDT];

    const int which = blockIdx.z;
    const float* w = (which == 0) ? wq : (which == 1) ? wk : wv;
    const int n0 = blockIdx.x * 128;
    const int m0 = blockIdx.y * 128;
    const int tid = threadIdx.x;
    const int lane = tid & 63, wid = tid >> 6;
    const int wr = wid >> 1, wc = wid & 1;
    const int r = lane & 15, g = lane >> 4;

    f32x4 acc[4][4];
    #pragma unroll
    for (int i = 0; i < 4; ++i)
        #pragma unroll
        for (int j = 0; j < 4; ++j) acc[i][j] = (f32x4){0.f, 0.f, 0.f, 0.f};

    for (int k0 = 0; k0 < DI; k0 += 32) {
        // stage A: x[m0..m0+128)[k0..k0+32) fp32 -> bf16 LDS
        #pragma unroll
        for (int i = 0; i < 4; ++i) {
            int idx = tid + i * 256;           // 1024 float4
            int row = idx >> 3, c4 = (idx & 7) * 4;
            const float4 v = *(const float4*)(x + (size_t)(m0 + row) * DI + k0 + c4);
            ushort4 pk; pk.x = f2bf(v.x); pk.y = f2bf(v.y); pk.z = f2bf(v.z); pk.w = f2bf(v.w);
            *(ushort4*)&As[row * LDT + c4] = pk;
        }
        // stage B transposed: Bs[n][k] = w[k0+k][n0+n]
        #pragma unroll
        for (int i = 0; i < 4; ++i) {
            int idx = tid + i * 256;
            int nn = (idx & 31) * 4, kk = idx >> 5;
            const float4 v = *(const float4*)(w + (size_t)(k0 + kk) * DI + n0 + nn);
            Bs[(nn + 0) * LDT + kk] = f2bf(v.x);
            Bs[(nn + 1) * LDT + kk] = f2bf(v.y);
            Bs[(nn + 2) * LDT + kk] = f2bf(v.z);
            Bs[(nn + 3) * LDT + kk] = f2bf(v.w);
        }
        __syncthreads();
        s16x8 af[4], bfr[4];
        #pragma unroll
        for (int fr = 0; fr < 4; ++fr)
            af[fr] = *(const s16x8*)&As[(wr * 64 + fr * 16 + r) * LDT + g * 8];
        #pragma unroll
        for (int cf = 0; cf < 4; ++cf)
            bfr[cf] = *(const s16x8*)&Bs[(wc * 64 + cf * 16 + r) * LDT + g * 8];
        #pragma unroll
        for (int fr = 0; fr < 4; ++fr)
            #pragma unroll
            for (int cf = 0; cf < 4; ++cf)
                acc[fr][cf] = __builtin_amdgcn_mfma_f32_16x16x32_bf16(af[fr], bfr[cf], acc[fr][cf], 0, 0, 0);
        __syncthreads();
    }

    const float scale = (which == 0) ? 0.03608439182435161f : 1.0f; // 1/sqrt(768) folded into Q
    if (which < 2) {
        unsigned short* O = ws + (size_t)which * QK_ELEMS;
        #pragma unroll
        for (int fr = 0; fr < 4; ++fr)
            #pragma unroll
            for (int cf = 0; cf < 4; ++cf) {
                int row = m0 + wr * 64 + fr * 16 + g * 4;
                int col = n0 + wc * 64 + cf * 16 + r;
                #pragma unroll
                for (int jj = 0; jj < 4; ++jj)
                    O[(size_t)(row + jj) * DI + col] = f2bf(acc[fr][cf][jj] * scale);
            }
    } else {
        unsigned short* O = ws + 2 * QK_ELEMS; // Vt[b][e][s]
        #pragma unroll
        for (int fr = 0; fr < 4; ++fr)
            #pragma unroll
            for (int cf = 0; cf < 4; ++cf) {
                int row = m0 + wr * 64 + fr * 16 + g * 4; // = b*2048 + s
                int b = row >> 11, s = row & 2047;
                int col = n0 + wc * 64 + cf * 16 + r;     // e
                ushort4 pk;
                pk.x = f2bf(acc[fr][cf][0]); pk.y = f2bf(acc[fr][cf][1]);
                pk.z = f2bf(acc[fr][cf][2]); pk.w = f2bf(acc[fr][cf][3]);
                *(ushort4*)&O[(size_t)b * DI * SS + (size_t)col * SS + s] = pk;
            }
    }
}

// ---------------- fused causal attention -------------------------------------
// Per wave: 16 q-rows x 384 out-cols, KVBLK=32, swapped QK^T (mfma(K,Q)) keeps
// P row-local per lane; PV via 16x16x16 bf16 MFMA whose A-layout == S^T D-layout.
// Block = 4 waves: q-blocks {j, 127-j} x out-halves -> constant work per block.
__global__ __launch_bounds__(256, 2) void attn_kernel(
    const unsigned short* __restrict__ ws, float* __restrict__ out)
{
    const unsigned short* Q  = ws;
    const unsigned short* K  = ws + QK_ELEMS;
    const unsigned short* Vt = ws + 2 * QK_ELEMS;

    const int id = blockIdx.x;
    const int b = id & 7;          // one batch per XCD (round-robin dispatch)
    const int jp = id >> 3;        // 0..63
    const int w = threadIdx.x >> 6;
    const int lane = threadIdx.x & 63;
    const int j = (w >> 1) ? (127 - jp) : jp;
    const int h = w & 1;
    const int q0 = j * 16;
    const int e0 = h * 384;
    const int r = lane & 15, g = lane >> 4;

    const unsigned short* Qb = Q + (size_t)b * SS * DI;
    const unsigned short* Kb = K + (size_t)b * SS * DI;
    const unsigned short* Vb = Vt + (size_t)b * DI * SS;

    // resident Q fragments (B-operand of swapped QK^T): lane holds row q0+r
    s16x8 qf[24];
    #pragma unroll
    for (int t = 0; t < 24; ++t)
        qf[t] = *(const s16x8*)(Qb + (size_t)(q0 + r) * DI + t * 32 + g * 8);

    f32x4 acc[24];
    #pragma unroll
    for (int cf = 0; cf < 24; ++cf) acc[cf] = (f32x4){0.f, 0.f, 0.f, 0.f};
    float m = -1e30f, l = 0.f;

    const int nt = (q0 + 15) / 32 + 1;
    for (int kt = 0; kt < nt; ++kt) {
        const int k0 = kt * 32;
        f32x4 s0 = {0.f, 0.f, 0.f, 0.f}, s1 = {0.f, 0.f, 0.f, 0.f};
        #pragma unroll
        for (int t = 0; t < 24; ++t) {
            s16x8 a0 = *(const s16x8*)(Kb + (size_t)(k0 + r) * DI + t * 32 + g * 8);
            s16x8 a1 = *(const s16x8*)(Kb + (size_t)(k0 + 16 + r) * DI + t * 32 + g * 8);
            s0 = __builtin_amdgcn_mfma_f32_16x16x32_bf16(a0, qf[t], s0, 0, 0, 0);
            s1 = __builtin_amdgcn_mfma_f32_16x16x32_bf16(a1, qf[t], s1, 0, 0, 0);
        }
        // causal mask (lane&15 = q-row r; reg jj at k-idx 4g+jj / 16+4g+jj)
        if (k0 + 31 > q0) {
            #pragma unroll
            for (int jj = 0; jj < 4; ++jj) {
                if (k0 + 4 * g + jj > q0 + r)      s0[jj] = -1e30f;
                if (k0 + 16 + 4 * g + jj > q0 + r) s1[jj] = -1e30f;
            }
        }
        // online softmax, fully per-lane (row r), reduce across g-groups
        float v = s0[0];
        #pragma unroll
        for (int jj = 1; jj < 4; ++jj) v = fmaxf(v, s0[jj]);
        #pragma unroll
        for (int jj = 0; jj < 4; ++jj) v = fmaxf(v, s1[jj]);
        v = fmaxf(v, __shfl_xor(v, 16));
        v = fmaxf(v, __shfl_xor(v, 32));
        const float mn = fmaxf(m, v);
        const float alpha = __expf(m - mn);
        float p0[4], p1[4], rs = 0.f;
        #pragma unroll
        for (int jj = 0; jj < 4; ++jj) {
            p0[jj] = __expf(s0[jj] - mn);
            p1[jj] = __expf(s1[jj] - mn);
            rs += p0[jj] + p1[jj];
        }
        rs += __shfl_xor(rs, 16);
        rs += __shfl_xor(rs, 32);
        l = l * alpha + rs; m = mn;
        // rescale accumulator (acc rows are 4g+jj; alpha lives at lane==row)
        float al[4];
        #pragma unroll
        for (int jj = 0; jj < 4; ++jj) al[jj] = __shfl(alpha, 4 * g + jj);
        #pragma unroll
        for (int cf = 0; cf < 24; ++cf)
            #pragma unroll
            for (int jj = 0; jj < 4; ++jj) acc[cf][jj] *= al[jj];
        // P -> bf16 A-frags of 16x16x16 (exact in-lane layout match)
        s16x4 pa0, pa1;
        #pragma unroll
        for (int jj = 0; jj < 4; ++jj) {
            pa0[jj] = (short)f2bf(p0[jj]);
            pa1[jj] = (short)f2bf(p1[jj]);
        }
        // PV: out[r][c] += sum_kk P[r][kk] * V[k0+kk][e0+c]
        #pragma unroll
        for (int cf = 0; cf < 24; ++cf) {
            const unsigned short* vrow = Vb + (size_t)(e0 + cf * 16 + r) * SS + k0;
            s16x4 vb0 = *(const s16x4*)(vrow + 4 * g);
            s16x4 vb1 = *(const s16x4*)(vrow + 16 + 4 * g);
            acc[cf] = __builtin_amdgcn_mfma_f32_16x16x16bf16_1k(pa0, vb0, acc[cf], 0, 0, 0);
            acc[cf] = __builtin_amdgcn_mfma_f32_16x16x16bf16_1k(pa1, vb1, acc[cf], 0, 0, 0);
        }
    }
    // epilogue: divide by row-sum, write fp32
    float linv[4];
    #pragma unroll
    for (int jj = 0; jj < 4; ++jj) linv[jj] = 1.0f / __shfl(l, 4 * g + jj);
    float* Ob = out + (size_t)b * SS * DI;
    #pragma unroll
    for (int cf = 0; cf < 24; ++cf)
        #pragma unroll
        for (int jj = 0; jj < 4; ++jj)
            Ob[(size_t)(q0 + 4 * g + jj) * DI + e0 + cf * 16 + r] = acc[cf][jj] * linv[jj];
}

extern "C" void kernel_launch(void* const* d_in, const int* in_sizes, int n_in,
                              void* d_out, int out_size, void* d_ws, size_t ws_size,
                              hipStream_t stream) {
    const float* x  = (const float*)d_in[0];
    const float* wq = (const float*)d_in[1];
    const float* wk = (const float*)d_in[2];
    const float* wv = (const float*)d_in[3];
    unsigned short* ws = (unsigned short*)d_ws;
    float* out = (float*)d_out;

    proj_kernel<<<dim3(6, 128, 3), 256, 0, stream>>>(x, wq, wk, wv, ws);
    attn_kernel<<<512, 256, 0, stream>>>(ws, out);
}